// Round 6
// baseline (311.121 us; speedup 1.0000x reference)
//
#include <hip/hip_runtime.h>
#include <hip/hip_bf16.h>

typedef _Float16 f16;
typedef f16 f16x8 __attribute__((ext_vector_type(8)));
typedef f16 f16x4 __attribute__((ext_vector_type(4)));
typedef f16 hf2 __attribute__((ext_vector_type(2)));
typedef float f32x4 __attribute__((ext_vector_type(4)));

#define QL 1024
#define KL 1024
#define DKD 64
#define NH 8
#define LNEPS 1e-5f

// ---- prep: f32 -> f16 plane with scale (K: scale=1, Q: scale=1/8) ----
__global__ __launch_bounds__(256) void prep_cvt(const float* __restrict__ src,
                                                f16* __restrict__ dst, float scale) {
  int i = (blockIdx.x * 256 + threadIdx.x) * 4;
  float4 v = *reinterpret_cast<const float4*>(src + i);
  f16x4 o;
  o[0] = (f16)(v.x * scale); o[1] = (f16)(v.y * scale);
  o[2] = (f16)(v.z * scale); o[3] = (f16)(v.w * scale);
  *reinterpret_cast<f16x4*>(dst + i) = o;
}

// ---- prep: V[bh][k][d] f32 -> vt[bh][d][k] f16 (transpose) ----
__global__ __launch_bounds__(256) void prep_vt(const float* __restrict__ V, f16* __restrict__ vt) {
  __shared__ float t[32][33];
  const int bh = blockIdx.z, k0 = blockIdx.x * 32, d0 = blockIdx.y * 32;
  const float* src = V + ((size_t)bh * KL + k0) * DKD + d0;
#pragma unroll
  for (int j = 0; j < 4; ++j) {
    int kk = threadIdx.y * 4 + j;
    t[kk][threadIdx.x] = src[kk * DKD + threadIdx.x];
  }
  __syncthreads();
  f16* dst = vt + ((size_t)bh * DKD + d0) * KL + k0;
#pragma unroll
  for (int j = 0; j < 4; ++j) {
    int dd = threadIdx.y * 4 + j;
    dst[dd * KL + threadIdx.x] = (f16)t[threadIdx.x][dd];
  }
}

// ---- pass 1: rowsum[bh][q] = sum_k exp(s); one head per block, XCD-local K ----
__global__ __launch_bounds__(256) void stats_kernel(const f16* __restrict__ qf,
    const f16* __restrict__ kf, float* __restrict__ rowsum) {
  const int tid = threadIdx.x;
  const int lane = tid & 63, w = tid >> 6;
  const int m = lane & 15, g = lane >> 4;
  const int id = blockIdx.x;
  const int bh = (id & 7) * 8 + ((id >> 3) & 7);   // batch id&7 -> XCD id&7
  const int q0 = (id >> 6) * 64 + w * 16;

  f16x8 qv[2];
#pragma unroll
  for (int dc = 0; dc < 2; ++dc)
    qv[dc] = *reinterpret_cast<const f16x8*>(
        qf + ((size_t)bh * QL + q0 + m) * DKD + dc * 32 + g * 8);

  float part[4] = {0.f, 0.f, 0.f, 0.f};
#pragma unroll 2
  for (int kt = 0; kt < 64; ++kt) {
    const f16* kb = kf + ((size_t)bh * KL + kt * 16 + m) * DKD + g * 8;
    f16x8 k0f = *reinterpret_cast<const f16x8*>(kb);
    f16x8 k1f = *reinterpret_cast<const f16x8*>(kb + 32);
    f32x4 acc = {0.f, 0.f, 0.f, 0.f};
    acc = __builtin_amdgcn_mfma_f32_16x16x32_f16(qv[0], k0f, acc, 0, 0, 0);
    acc = __builtin_amdgcn_mfma_f32_16x16x32_f16(qv[1], k1f, acc, 0, 0, 0);
#pragma unroll
    for (int ri = 0; ri < 4; ++ri) part[ri] += __expf(acc[ri]);
  }
#pragma unroll
  for (int ri = 0; ri < 4; ++ri) {
    float v = part[ri];
    v += __shfl_xor(v, 1); v += __shfl_xor(v, 2);
    v += __shfl_xor(v, 4); v += __shfl_xor(v, 8);
    part[ri] = v;
  }
  if (m == 0) {
#pragma unroll
    for (int ri = 0; ri < 4; ++ri) rowsum[(size_t)bh * QL + q0 + g * 4 + ri] = part[ri];
  }
}

// ---- pass 2 (split-k): S -> p -> mix -> LN -> att_map + partial PV ----
// Register diet for 4 waves/SIMD: Q frags reloaded from L2 each iter (frees
// 64 VGPR), inv_rs packed f16 (frees 16). PV(t-1) scheduled between S-MFMA(t)
// and exp/mix(t) to hide latency with independent work.
__global__ __launch_bounds__(256, 4) void main_kernel(
    const f16* __restrict__ qf, const f16* __restrict__ kf, const f16* __restrict__ vt,
    const float* __restrict__ rowsum,
    const float* __restrict__ hA, const float* __restrict__ lnw, const float* __restrict__ lnb,
    float* __restrict__ outp, float* __restrict__ part1, float* __restrict__ att_map) {
  __shared__ __align__(16) f16 y_lds[2][NH][16][64];

  const int tid = threadIdx.x;
  const int lane = tid & 63, w = tid >> 6;
  const int m = lane & 15, g = lane >> 4;
  const int id = blockIdx.x;
  const int b = id & 7, kc = (id >> 3) & 1, q0 = (id >> 4) * 16;  // batch b -> XCD b

  float haR[64], wR[8], bR[8];
#pragma unroll
  for (int j = 0; j < 64; ++j) haR[j] = hA[j];
#pragma unroll
  for (int j = 0; j < 8; ++j) { wR[j] = lnw[j]; bR[j] = lnb[j]; }

  // inv rowsum, packed as f16 pairs: irsP[h][rp] = (1/rs[g*4+2rp], 1/rs[g*4+2rp+1])
  hf2 irsP[NH][2];
#pragma unroll
  for (int h = 0; h < NH; ++h)
#pragma unroll
    for (int rp = 0; rp < 2; ++rp) {
      const float* rsp = rowsum + (size_t)(b * NH + h) * QL + q0 + g * 4 + 2 * rp;
      hf2 p;
      p[0] = (f16)(1.0f / rsp[0]);
      p[1] = (f16)(1.0f / rsp[1]);
      irsP[h][rp] = p;
    }

  const size_t hQ = (size_t)QL * DKD;   // per-head stride (elements)
  const f16* qrow = qf + ((size_t)(b * NH) * QL + q0 + m) * DKD + g * 8;

  f32x4 oacc[2][4];
#pragma unroll
  for (int hp = 0; hp < 2; ++hp)
#pragma unroll
    for (int dt = 0; dt < 4; ++dt) oacc[hp][dt] = (f32x4){0.f, 0.f, 0.f, 0.f};

  auto PV = [&](int bufi, int kb0) {
#pragma unroll
    for (int hp = 0; hp < 2; ++hp) {
      const int hh = w + hp * 4;
      const f16* vb = vt + (((size_t)(b * NH + hh)) * DKD + m) * KL + kb0 + g * 8;
#pragma unroll
      for (int ks = 0; ks < 2; ++ks) {
        const f16x8 af = *reinterpret_cast<const f16x8*>(
            &y_lds[bufi][hh][m][((ks * 4 + g) ^ (m & 7)) << 3]);
#pragma unroll
        for (int dt = 0; dt < 4; ++dt) {
          f16x8 vf = *reinterpret_cast<const f16x8*>(vb + (size_t)dt * 16 * KL + ks * 32);
          oacc[hp][dt] = __builtin_amdgcn_mfma_f32_16x16x32_f16(af, vf, oacc[hp][dt], 0, 0, 0);
        }
      }
    }
  };

#pragma unroll 2
  for (int kt = 0; kt < 8; ++kt) {
    const int kbase = kc * 512 + kt * 64;
    const int kcol = kbase + w * 16;
    const int buf = kt & 1;

    // S phase: 8 heads, columns kcol+m; Q reloaded from L2 (register diet)
    f32x4 pacc[NH];
    {
      const f16* kb = kf + ((size_t)(b * NH) * KL + kcol + m) * DKD + g * 8;
#pragma unroll
      for (int h = 0; h < NH; ++h) {
        const f16* qp = qrow + h * hQ;
        f16x8 q0f = *reinterpret_cast<const f16x8*>(qp);
        f16x8 q1f = *reinterpret_cast<const f16x8*>(qp + 32);
        const f16* kh = kb + h * (size_t)KL * DKD;
        f16x8 k0f = *reinterpret_cast<const f16x8*>(kh);
        f16x8 k1f = *reinterpret_cast<const f16x8*>(kh + 32);
        f32x4 acc = {0.f, 0.f, 0.f, 0.f};
        acc = __builtin_amdgcn_mfma_f32_16x16x32_f16(q0f, k0f, acc, 0, 0, 0);
        acc = __builtin_amdgcn_mfma_f32_16x16x32_f16(q1f, k1f, acc, 0, 0, 0);
        pacc[h] = acc;
      }
    }

    // PV of previous tile: independent work, hides S-MFMA + load latency
    if (kt) PV(buf ^ 1, kbase - 64);

    // p = exp(s) * inv_rowsum
#pragma unroll
    for (int h = 0; h < NH; ++h) {
      pacc[h][0] = __expf(pacc[h][0]) * (float)irsP[h][0][0];
      pacc[h][1] = __expf(pacc[h][1]) * (float)irsP[h][0][1];
      pacc[h][2] = __expf(pacc[h][2]) * (float)irsP[h][1][0];
      pacc[h][3] = __expf(pacc[h][3]) * (float)irsP[h][1][1];
    }

    // mix + LN + att_map + y -> LDS (swizzled; verified 0 bank conflicts)
#pragma unroll
    for (int ri = 0; ri < 4; ++ri) {
      const int qq = g * 4 + ri;
      float mixed[8];
      float mu = 0.f;
#pragma unroll
      for (int hh = 0; hh < 8; ++hh) {
        float s = 0.f;
#pragma unroll
        for (int j = 0; j < 8; ++j) s = fmaf(pacc[j][ri], haR[j * 8 + hh], s);
        mixed[hh] = s; mu += s;
      }
      mu *= 0.125f;
      float var = 0.f;
#pragma unroll
      for (int hh = 0; hh < 8; ++hh) { float d = mixed[hh] - mu; var = fmaf(d, d, var); }
      var *= 0.125f;
      const float rsv = rsqrtf(var + LNEPS);
      float am = 0.f;
      const int kidx = ((((2 * w + (m >> 3)) ^ (qq & 7)) << 3) | (m & 7));
#pragma unroll
      for (int hh = 0; hh < 8; ++hh) {
        float y = (mixed[hh] - mu) * rsv * wR[hh] + bR[hh];
        am += y;
        y_lds[buf][hh][qq][kidx] = (f16)y;
      }
      att_map[((size_t)b * QL + q0 + qq) * KL + kcol + m] = am * 0.125f;
    }
    __syncthreads();  // y(kt) complete before PV(kt) next iter; dbuf covers WAR
  }
  PV(1, kc * 512 + 448);  // drain last tile

  // epilogue: kc=0 -> outp, kc=1 -> partial (reduced later)
  float* dst = kc ? part1 : outp;
#pragma unroll
  for (int hp = 0; hp < 2; ++hp) {
    const int hh = w + hp * 4;
#pragma unroll
    for (int dt = 0; dt < 4; ++dt)
#pragma unroll
      for (int ri = 0; ri < 4; ++ri)
        dst[(((size_t)(b * NH + hh)) * QL + q0 + g * 4 + ri) * DKD + dt * 16 + m] =
            oacc[hp][dt][ri];
  }
}

// ---- out += partial ----
__global__ __launch_bounds__(256) void reduce_kernel(const float* __restrict__ p1,
                                                     float* __restrict__ outp) {
  size_t i = ((size_t)blockIdx.x * 256 + threadIdx.x) * 4;
  float4 a = *reinterpret_cast<const float4*>(outp + i);
  float4 c = *reinterpret_cast<const float4*>(p1 + i);
  a.x += c.x; a.y += c.y; a.z += c.z; a.w += c.w;
  *reinterpret_cast<float4*>(outp + i) = a;
}

extern "C" void kernel_launch(void* const* d_in, const int* in_sizes, int n_in,
                              void* d_out, int out_size, void* d_ws, size_t ws_size,
                              hipStream_t stream) {
  const float* Qm  = (const float*)d_in[0];
  const float* Km  = (const float*)d_in[1];
  const float* Vm  = (const float*)d_in[2];
  const float* hA  = (const float*)d_in[3];
  const float* lnw = (const float*)d_in[4];
  const float* lnb = (const float*)d_in[5];
  float* outp = (float*)d_out;
  float* att_map = outp + (size_t)64 * QL * DKD;

  char* ws = (char*)d_ws;
  f16* kfp   = (f16*)ws;                                   // 8 MB
  f16* vtp   = (f16*)(ws + (size_t)8388608);               // 8 MB
  f16* qfp   = (f16*)(ws + (size_t)16777216);              // 8 MB
  float* rsm = (float*)(ws + (size_t)25165824);            // 256 KB
  float* p1  = (float*)(ws + (size_t)25427968);            // 16.8 MB

  prep_cvt<<<4096, 256, 0, stream>>>(Km, kfp, 1.0f);
  prep_cvt<<<4096, 256, 0, stream>>>(Qm, qfp, 0.125f);
  prep_vt<<<dim3(32, 2, 64), dim3(32, 8), 0, stream>>>(Vm, vtp);
  stats_kernel<<<1024, 256, 0, stream>>>(qfp, kfp, rsm);
  main_kernel<<<1024, 256, 0, stream>>>(qfp, kfp, vtp, rsm, hA, lnw, lnb, outp, p1, att_map);
  reduce_kernel<<<4096, 256, 0, stream>>>(p1, outp);
}